// Round 1
// 468.576 us; speedup vs baseline: 1.1851x; 1.1851x over previous
//
#include <hip/hip_runtime.h>
#include <math.h>

namespace {
constexpr int B_ = 4;
constexpr int N_ = 2048;
constexpr int K_ = 48;
constexpr int MAX_REL_ = 32;
constexpr int EDGE_C_ = 128;
constexpr int PE_IN_ = 66;    // 2*MAX_REL + 2 (only d in [0,64] reachable: chain_labels==0)
constexpr int NUM_PE_ = 16;
constexpr int NROWS = B_ * N_;      // 8192
constexpr int NEDGE = NROWS * K_;   // 393216
constexpr int C1_ROWS = 2 * MAX_REL_ + 1;   // 65 reachable doff values
}

// ---------------- kernel 1: X = coords[center] * mask ----------------
__global__ __launch_bounds__(256) void x_kernel(const float* __restrict__ coords,
                                                const float* __restrict__ mask,
                                                const int* __restrict__ t2ca,
                                                float* __restrict__ X) {
    int r = blockIdx.x * 256 + threadIdx.x;
    if (r >= NROWS) return;
    int b = r >> 11;                 // N_ = 2048
    int c = t2ca[r];
    float m = mask[r];
    const float* s = coords + ((size_t)(b * N_ + c)) * 3;
    X[r * 3 + 0] = __fmul_rn(s[0], m);
    X[r * 3 + 1] = __fmul_rn(s[1], m);
    X[r * 3 + 2] = __fmul_rn(s[2], m);
}

// ---------------- kernel 1b: C1[d][c] = (pe_w[d,:]+pe_b) @ edge_w[0:16,c] ----
// The positional-encoding half of the 33x128 matmul depends only on
// doff in [0,64] -> precompute the 65x128 result table once (33 KB, L1-hot).
__global__ __launch_bounds__(256) void c1_kernel(const float* __restrict__ pe_w,
                                                 const float* __restrict__ pe_b,
                                                 const float* __restrict__ edge_w,
                                                 float* __restrict__ C1) {
    int idx = blockIdx.x * 256 + threadIdx.x;
    if (idx >= C1_ROWS * EDGE_C_) return;
    int d = idx >> 7, c = idx & 127;
    float acc = 0.0f;
    #pragma unroll
    for (int p = 0; p < NUM_PE_; ++p)
        acc = fmaf(pe_w[d * NUM_PE_ + p] + pe_b[p], edge_w[p * EDGE_C_ + c], acc);
    C1[idx] = acc;
}

// ---------------- kernel 2: masked distances + stable top-K (smallest) --------
// One wave (64 lanes) per row; 4 rows per 256-thread block.  (unchanged)
__global__ __launch_bounds__(256) void knn_kernel(const float* __restrict__ X,
                                                  const float* __restrict__ mask,
                                                  float* __restrict__ eidx_f,
                                                  float* __restrict__ dneb) {
    __shared__ float sdist[4][N_];   // 32 KB
    const int wave = threadIdx.x >> 6;
    const int lane = threadIdx.x & 63;
    const int row = blockIdx.x * 4 + wave;   // grid = NROWS/4, always in range
    const int b = row >> 11;
    float* dist = sdist[wave];

    const float xi0 = X[row * 3 + 0];
    const float xi1 = X[row * 3 + 1];
    const float xi2 = X[row * 3 + 2];
    const float mi = mask[row];
    const float* Xb = X + (size_t)b * N_ * 3;
    const float* mb = mask + b * N_;

    // pass 1: D = m2 * sqrt(fma-chain + 1e-6), row max
    float lmax = -INFINITY;
    #pragma unroll 4
    for (int t = 0; t < N_ / 64; ++t) {
        int j = t * 64 + lane;
        float dx = __fsub_rn(xi0, Xb[j * 3 + 0]);
        float dy = __fsub_rn(xi1, Xb[j * 3 + 1]);
        float dz = __fsub_rn(xi2, Xb[j * 3 + 2]);
        float d2 = __fmaf_rn(dz, dz, __fmaf_rn(dx, dx, __fmul_rn(dy, dy)));
        float m2 = __fmul_rn(mi, mb[j]);
        float d = __fmul_rn(m2, __fsqrt_rn(__fadd_rn(d2, 1e-6f)));
        dist[j] = d;
        lmax = fmaxf(lmax, d);
    }
    #pragma unroll
    for (int off = 32; off; off >>= 1) lmax = fmaxf(lmax, __shfl_xor(lmax, off, 64));

    // pass 2: D_adjust = D + (1-m2)*Dmax; per-lane chunk min (ties: lowest j)
    float cv = INFINITY; int ci = 0x7FFFFFFF;
    #pragma unroll 4
    for (int t = 0; t < N_ / 64; ++t) {
        int j = t * 64 + lane;
        float m2 = __fmul_rn(mi, mb[j]);
        float d = __fadd_rn(dist[j], __fmul_rn(__fsub_rn(1.0f, m2), lmax));
        dist[j] = d;
        if (d < cv) { cv = d; ci = j; }
    }

    // 48 extraction rounds: global lexicographic (val asc, idx asc) min
    float keep_v = 0.0f; int keep_i = 0;
    for (int k = 0; k < K_; ++k) {
        float v = cv; int idx = ci;
        #pragma unroll
        for (int off = 32; off; off >>= 1) {
            float ov = __shfl_xor(v, off, 64);
            int oi = __shfl_xor(idx, off, 64);
            if (ov < v || (ov == v && oi < idx)) { v = ov; idx = oi; }
        }
        if ((idx & 63) == lane) {          // owner removes + rescans its chunk
            dist[idx] = INFINITY;
            float nv = INFINITY; int ni = 0x7FFFFFFF;
            #pragma unroll 8
            for (int t = 0; t < N_ / 64; ++t) {
                int j = t * 64 + lane;
                float d = dist[j];
                if (d < nv) { nv = d; ni = j; }
            }
            cv = nv; ci = ni;
        }
        if (lane == k) { keep_v = v; keep_i = idx; }
    }
    if (lane < K_) {
        dneb[(size_t)row * K_ + lane] = keep_v;
        eidx_f[(size_t)row * K_ + lane] = (float)keep_i;   // exact int-in-float
    }
}

// ---------------- kernel 3: features -> matmul -> LayerNorm ----------
// One WAVE per row (48 edges). Phase A: all 48 edges' metadata gathered in
// parallel across lanes (latency paid once per row, not chained per edge).
// Phase B: all 48x16 RBF exps computed cooperatively into LDS.
// Phase C: per edge, pe-part comes from the precomputed C1 table (one float2
// load), rbf from 4 broadcast ds_read_b128, bond via uniform branch.
// Each lane owns channels (2*lane, 2*lane+1); only 17 weight columns
// (rbf+bond) live in registers -> they actually fit now.
__global__ __launch_bounds__(256, 4) void edge_kernel(const float* __restrict__ eidx_f,
                                                      const float* __restrict__ dneb,
                                                      const float* __restrict__ token_bonds,
                                                      const float* __restrict__ C1,
                                                      const float* __restrict__ edge_w,
                                                      const float* __restrict__ ln_g,
                                                      const float* __restrict__ ln_b,
                                                      const int* __restrict__ res_idx,
                                                      const int* __restrict__ is_lig,
                                                      float* __restrict__ Eout) {
    __shared__ float s_rbf[4][K_][NUM_PE_];   // 12 KB
    __shared__ float s_D[4][K_];              // 768 B
    const int tid = threadIdx.x;
    const int wv = tid >> 6;
    const int lane = tid & 63;
    const int row = blockIdx.x * 4 + wv;      // grid = NROWS/4, one row per wave
    const int b = row >> 11;

    // rbf (16) + bond (1) weight columns for this lane's two channels: 34 VGPRs
    float w0[17], w1[17];
    #pragma unroll
    for (int p = 0; p < 17; ++p) {
        float2 w = ((const float2*)edge_w)[(NUM_PE_ + p) * 64 + lane];
        w0[p] = w.x; w1[p] = w.y;
    }
    const float g0 = ln_g[2 * lane], g1 = ln_g[2 * lane + 1];
    const float bb0 = ln_b[2 * lane], bb1 = ln_b[2 * lane + 1];

    const int ri = res_idx[row];
    const int li = is_lig[row];

    // ---- phase A: batched per-edge metadata (lanes 0..47, all in flight) ----
    int doff_l = 0; float tb_l = 0.0f;
    if (lane < K_) {
        const int e = row * K_ + lane;
        const int j = (int)(eidx_f[e] + 0.5f);
        const float D = dneb[e];
        const int jrow = b * N_ + j;
        const int rj = res_idx[jrow];
        const int lj = is_lig[jrow];
        float tb = token_bonds[(size_t)row * N_ + j];
        tb_l = (li | lj) ? tb : 0.0f;
        doff_l = min(max(ri - rj + MAX_REL_, 0), 2 * MAX_REL_);
        s_D[wv][lane] = D;
    }
    __syncthreads();

    // ---- phase B: all 48x16 RBF values cooperatively (12 exps per lane) ----
    #pragma unroll
    for (int t = 0; t < (K_ * NUM_PE_) / 64; ++t) {
        const int idx = t * 64 + lane;
        const int k = idx >> 4, r = idx & 15;
        const float D = s_D[wv][k];
        const float mu = 2.0f + (float)r * (4.0f / 3.0f);
        const float x = (D - mu) * 0.8f;     // /1.25
        s_rbf[wv][k][r] = __expf(-x * x);
    }
    __syncthreads();

    // ---- phase C: 48 edges, no global-latency chains in the loop ----
    float2* outp = (float2*)Eout + (size_t)row * K_ * 64 + lane;
    #pragma unroll 2
    for (int k = 0; k < K_; ++k) {
        const int doffk = __shfl(doff_l, k, 64);
        const float tbk = __shfl(tb_l, k, 64);
        // pe-part of the matmul: precomputed row of C1 (L1-hot, 512 B/wave)
        const float2 c1 = *(const float2*)(C1 + ((size_t)doffk << 7) + 2 * lane);

        float rr[16];
        *(float4*)&rr[0]  = *(const float4*)&s_rbf[wv][k][0];
        *(float4*)&rr[4]  = *(const float4*)&s_rbf[wv][k][4];
        *(float4*)&rr[8]  = *(const float4*)&s_rbf[wv][k][8];
        *(float4*)&rr[12] = *(const float4*)&s_rbf[wv][k][12];

        float ax = 0.0f, ay = 0.0f;
        #pragma unroll
        for (int p = 0; p < 16; ++p) {
            ax = fmaf(rr[p], w0[p], ax);
            ay = fmaf(rr[p], w1[p], ay);
        }
        if (tbk != 0.0f) {                 // wave-uniform branch, ~1% taken
            ax = fmaf(tbk, w0[16], ax);
            ay = fmaf(tbk, w1[16], ay);
        }
        ax += c1.x; ay += c1.y;

        // LayerNorm over 128 channels (2 per lane)
        float s = ax + ay, sq = fmaf(ax, ax, ay * ay);
        #pragma unroll
        for (int off = 32; off; off >>= 1) {
            s  += __shfl_xor(s, off, 64);
            sq += __shfl_xor(sq, off, 64);
        }
        const float mu = s * (1.0f / 128.0f);
        const float var = sq * (1.0f / 128.0f) - mu * mu;
        const float rstd = rsqrtf(var + 1e-5f);
        const float ox = (ax - mu) * rstd * g0 + bb0;
        const float oy = (ay - mu) * rstd * g1 + bb1;
        outp[(size_t)k * 64] = make_float2(ox, oy);
    }
}

extern "C" void kernel_launch(void* const* d_in, const int* in_sizes, int n_in,
                              void* d_out, int out_size, void* d_ws, size_t ws_size,
                              hipStream_t stream) {
    const float* coords      = (const float*)d_in[0];
    const float* mask        = (const float*)d_in[1];
    const float* token_bonds = (const float*)d_in[2];
    const float* pe_w        = (const float*)d_in[3];
    const float* pe_b        = (const float*)d_in[4];
    const float* edge_w      = (const float*)d_in[5];
    const float* ln_g        = (const float*)d_in[6];
    const float* ln_b        = (const float*)d_in[7];
    const int*   t2ca        = (const int*)d_in[8];
    const int*   res_idx     = (const int*)d_in[9];
    // d_in[10] (asym_id) unused: chain_labels = zeros in the reference
    const int*   is_lig      = (const int*)d_in[11];

    float* out    = (float*)d_out;
    float* Eout   = out;                               // NEDGE * 128
    float* eidx_f = out + (size_t)NEDGE * EDGE_C_;     // NEDGE (ints as floats)
    float* dneb   = eidx_f + NEDGE;                    // NEDGE

    float* X  = (float*)d_ws;                          // NROWS*3 floats (96 KB)
    float* C1 = X + (size_t)NROWS * 3;                 // 65*128 floats (33 KB)

    hipLaunchKernelGGL(x_kernel, dim3(NROWS / 256), dim3(256), 0, stream,
                       coords, mask, t2ca, X);
    hipLaunchKernelGGL(c1_kernel, dim3((C1_ROWS * EDGE_C_ + 255) / 256), dim3(256), 0, stream,
                       pe_w, pe_b, edge_w, C1);
    hipLaunchKernelGGL(knn_kernel, dim3(NROWS / 4), dim3(256), 0, stream,
                       X, mask, eidx_f, dneb);
    hipLaunchKernelGGL(edge_kernel, dim3(NROWS / 4), dim3(256), 0, stream,
                       eidx_f, dneb, token_bonds, C1, edge_w,
                       ln_g, ln_b, res_idx, is_lig, Eout);
}

// Round 2
// 443.567 us; speedup vs baseline: 1.2520x; 1.0564x over previous
//
#include <hip/hip_runtime.h>
#include <math.h>

namespace {
constexpr int B_ = 4;
constexpr int N_ = 2048;
constexpr int K_ = 48;
constexpr int MAX_REL_ = 32;
constexpr int EDGE_C_ = 128;
constexpr int NUM_PE_ = 16;
constexpr int NROWS = B_ * N_;      // 8192
constexpr int NEDGE = NROWS * K_;   // 393216
constexpr int C1_ROWS = 2 * MAX_REL_ + 1;   // 65 reachable doff values
}

// ---------------- kernel 1: X = coords[center] * mask ----------------
__global__ __launch_bounds__(256) void x_kernel(const float* __restrict__ coords,
                                                const float* __restrict__ mask,
                                                const int* __restrict__ t2ca,
                                                float* __restrict__ X) {
    int r = blockIdx.x * 256 + threadIdx.x;
    if (r >= NROWS) return;
    int b = r >> 11;                 // N_ = 2048
    int c = t2ca[r];
    float m = mask[r];
    const float* s = coords + ((size_t)(b * N_ + c)) * 3;
    X[r * 3 + 0] = __fmul_rn(s[0], m);
    X[r * 3 + 1] = __fmul_rn(s[1], m);
    X[r * 3 + 2] = __fmul_rn(s[2], m);
}

// ---------------- kernel 1b: C1[d][c] = (pe_w[d,:]+pe_b) @ edge_w[0:16,c] ----
__global__ __launch_bounds__(256) void c1_kernel(const float* __restrict__ pe_w,
                                                 const float* __restrict__ pe_b,
                                                 const float* __restrict__ edge_w,
                                                 float* __restrict__ C1) {
    int idx = blockIdx.x * 256 + threadIdx.x;
    if (idx >= C1_ROWS * EDGE_C_) return;
    int d = idx >> 7, c = idx & 127;
    float acc = 0.0f;
    #pragma unroll
    for (int p = 0; p < NUM_PE_; ++p)
        acc = fmaf(pe_w[d * NUM_PE_ + p] + pe_b[p], edge_w[p * EDGE_C_ + c], acc);
    C1[idx] = acc;
}

// ---------------- kernel 2: masked distances + stable top-K (smallest) --------
// One wave per row; 2 rows per 128-thread block.
// Selection via per-lane register bitonic sort of 32-element chunks packed
// into uint64 keys (float bits << 11 | index): uint64 order == (d asc, idx asc)
// since d_adj >= 0.  Extraction = 48 rounds of u64 butterfly min + winner pops
// its next sorted element from LDS (no rescans).
__global__ __launch_bounds__(128) void knn_kernel(const float* __restrict__ X,
                                                  const float* __restrict__ mask,
                                                  float* __restrict__ eidx_f,
                                                  float* __restrict__ dneb) {
    __shared__ unsigned long long skey[2][32][64];   // 32 KB: [wave][t][lane]
    const int wv = threadIdx.x >> 6;
    const int lane = threadIdx.x & 63;
    const int row = blockIdx.x * 2 + wv;     // grid = NROWS/2
    const int b = row >> 11;

    const float xi0 = X[row * 3 + 0];
    const float xi1 = X[row * 3 + 1];
    const float xi2 = X[row * 3 + 2];
    const float mi = mask[row];
    const float* Xb = X + (size_t)b * N_ * 3;
    const float* mb = mask + b * N_;

    // pass 1: D = m2 * sqrt(fma-chain + 1e-6) into registers, row max
    float d[32];
    float lmax = -INFINITY;
    #pragma unroll
    for (int t = 0; t < 32; ++t) {
        int j = t * 64 + lane;
        float dx = __fsub_rn(xi0, Xb[j * 3 + 0]);
        float dy = __fsub_rn(xi1, Xb[j * 3 + 1]);
        float dz = __fsub_rn(xi2, Xb[j * 3 + 2]);
        float d2 = __fmaf_rn(dz, dz, __fmaf_rn(dx, dx, __fmul_rn(dy, dy)));
        float m2 = __fmul_rn(mi, mb[j]);
        float dd = __fmul_rn(m2, __fsqrt_rn(__fadd_rn(d2, 1e-6f)));
        d[t] = dd;
        lmax = fmaxf(lmax, dd);
    }
    #pragma unroll
    for (int off = 32; off; off >>= 1) lmax = fmaxf(lmax, __shfl_xor(lmax, off, 64));

    // pass 2: D_adjust = D + (1-m2)*Dmax; pack (fbits << 11) | j
    unsigned long long key[32];
    #pragma unroll
    for (int t = 0; t < 32; ++t) {
        int j = t * 64 + lane;
        float m2 = __fmul_rn(mi, mb[j]);
        float adj = __fadd_rn(d[t], __fmul_rn(__fsub_rn(1.0f, m2), lmax));
        key[t] = ((unsigned long long)__float_as_uint(adj) << 11) | (unsigned long long)j;
    }

    // in-register bitonic sort, ascending, 32 elements (240 CEs, all compile-time)
    #pragma unroll
    for (int kk = 2; kk <= 32; kk <<= 1) {
        #pragma unroll
        for (int jj = kk >> 1; jj > 0; jj >>= 1) {
            #pragma unroll
            for (int i = 0; i < 32; ++i) {
                int l = i ^ jj;
                if (l > i) {
                    const bool dir = ((i & kk) == 0);   // compile-time
                    unsigned long long a = key[i], b2 = key[l];
                    unsigned long long lo = a < b2 ? a : b2;
                    unsigned long long hi = a < b2 ? b2 : a;
                    key[i] = dir ? lo : hi;
                    key[l] = dir ? hi : lo;
                }
            }
        }
    }

    // spill sorted chunk to LDS ([t][lane]: conflict-free), keep head+next in regs
    #pragma unroll
    for (int t = 0; t < 32; ++t) skey[wv][t][lane] = key[t];
    __syncthreads();   // (per-wave data only, but cheap and safe)

    unsigned long long hd = key[0];
    unsigned long long nxt = key[1];
    int ptr = 2;

    // 48 extraction rounds: global min of 64 heads; winner pops next element.
    unsigned long long res = 0;
    for (int k = 0; k < K_; ++k) {
        unsigned long long v = hd;
        #pragma unroll
        for (int off = 32; off; off >>= 1) {
            unsigned long long o = __shfl_xor(v, off, 64);
            v = (o < v) ? o : v;
        }
        if (hd == v) {                      // unique winner (keys distinct)
            hd = nxt;
            unsigned long long t = skey[wv][ptr & 31][lane];
            nxt = (ptr < 32) ? t : ~0ull;
            ++ptr;
        }
        if (lane == k) res = v;
    }

    if (lane < K_) {
        unsigned int fb = (unsigned int)(res >> 11);
        unsigned int ji = (unsigned int)(res & 2047u);
        dneb[(size_t)row * K_ + lane] = __uint_as_float(fb);
        eidx_f[(size_t)row * K_ + lane] = (float)ji;    // exact int-in-float
    }
}

// ---------------- kernel 3: features -> matmul -> LayerNorm ----------
// One WAVE per row (48 edges). Phase A: batched metadata gathers.
// Phase B: cooperative RBF exps into LDS. Phase C: per-edge matmul from
// precomputed C1 table + register weight columns, then wave LayerNorm.
__global__ __launch_bounds__(256, 4) void edge_kernel(const float* __restrict__ eidx_f,
                                                      const float* __restrict__ dneb,
                                                      const float* __restrict__ token_bonds,
                                                      const float* __restrict__ C1,
                                                      const float* __restrict__ edge_w,
                                                      const float* __restrict__ ln_g,
                                                      const float* __restrict__ ln_b,
                                                      const int* __restrict__ res_idx,
                                                      const int* __restrict__ is_lig,
                                                      float* __restrict__ Eout) {
    __shared__ float s_rbf[4][K_][NUM_PE_];   // 12 KB
    __shared__ float s_D[4][K_];              // 768 B
    const int tid = threadIdx.x;
    const int wv = tid >> 6;
    const int lane = tid & 63;
    const int row = blockIdx.x * 4 + wv;      // grid = NROWS/4, one row per wave
    const int b = row >> 11;

    // rbf (16) + bond (1) weight columns for this lane's two channels
    float w0[17], w1[17];
    #pragma unroll
    for (int p = 0; p < 17; ++p) {
        float2 w = ((const float2*)edge_w)[(NUM_PE_ + p) * 64 + lane];
        w0[p] = w.x; w1[p] = w.y;
    }
    const float g0 = ln_g[2 * lane], g1 = ln_g[2 * lane + 1];
    const float bb0 = ln_b[2 * lane], bb1 = ln_b[2 * lane + 1];

    const int ri = res_idx[row];
    const int li = is_lig[row];

    // ---- phase A: batched per-edge metadata (lanes 0..47, all in flight) ----
    int doff_l = 0; float tb_l = 0.0f;
    if (lane < K_) {
        const int e = row * K_ + lane;
        const int j = (int)(eidx_f[e] + 0.5f);
        const float D = dneb[e];
        const int jrow = b * N_ + j;
        const int rj = res_idx[jrow];
        const int lj = is_lig[jrow];
        float tb = token_bonds[(size_t)row * N_ + j];
        tb_l = (li | lj) ? tb : 0.0f;
        doff_l = min(max(ri - rj + MAX_REL_, 0), 2 * MAX_REL_);
        s_D[wv][lane] = D;
    }
    __syncthreads();

    // ---- phase B: all 48x16 RBF values cooperatively (12 exps per lane) ----
    #pragma unroll
    for (int t = 0; t < (K_ * NUM_PE_) / 64; ++t) {
        const int idx = t * 64 + lane;
        const int k = idx >> 4, r = idx & 15;
        const float D = s_D[wv][k];
        const float mu = 2.0f + (float)r * (4.0f / 3.0f);
        const float x = (D - mu) * 0.8f;     // /1.25
        s_rbf[wv][k][r] = __expf(-x * x);
    }
    __syncthreads();

    // ---- phase C: 48 edges, no global-latency chains in the loop ----
    float2* outp = (float2*)Eout + (size_t)row * K_ * 64 + lane;
    #pragma unroll 2
    for (int k = 0; k < K_; ++k) {
        const int doffk = __shfl(doff_l, k, 64);
        const float tbk = __shfl(tb_l, k, 64);
        const float2 c1 = *(const float2*)(C1 + ((size_t)doffk << 7) + 2 * lane);

        float rr[16];
        *(float4*)&rr[0]  = *(const float4*)&s_rbf[wv][k][0];
        *(float4*)&rr[4]  = *(const float4*)&s_rbf[wv][k][4];
        *(float4*)&rr[8]  = *(const float4*)&s_rbf[wv][k][8];
        *(float4*)&rr[12] = *(const float4*)&s_rbf[wv][k][12];

        float ax = 0.0f, ay = 0.0f;
        #pragma unroll
        for (int p = 0; p < 16; ++p) {
            ax = fmaf(rr[p], w0[p], ax);
            ay = fmaf(rr[p], w1[p], ay);
        }
        if (tbk != 0.0f) {                 // wave-uniform branch, ~1% taken
            ax = fmaf(tbk, w0[16], ax);
            ay = fmaf(tbk, w1[16], ay);
        }
        ax += c1.x; ay += c1.y;

        // LayerNorm over 128 channels (2 per lane)
        float s = ax + ay, sq = fmaf(ax, ax, ay * ay);
        #pragma unroll
        for (int off = 32; off; off >>= 1) {
            s  += __shfl_xor(s, off, 64);
            sq += __shfl_xor(sq, off, 64);
        }
        const float mu = s * (1.0f / 128.0f);
        const float var = sq * (1.0f / 128.0f) - mu * mu;
        const float rstd = rsqrtf(var + 1e-5f);
        const float ox = (ax - mu) * rstd * g0 + bb0;
        const float oy = (ay - mu) * rstd * g1 + bb1;
        outp[(size_t)k * 64] = make_float2(ox, oy);
    }
}

extern "C" void kernel_launch(void* const* d_in, const int* in_sizes, int n_in,
                              void* d_out, int out_size, void* d_ws, size_t ws_size,
                              hipStream_t stream) {
    const float* coords      = (const float*)d_in[0];
    const float* mask        = (const float*)d_in[1];
    const float* token_bonds = (const float*)d_in[2];
    const float* pe_w        = (const float*)d_in[3];
    const float* pe_b        = (const float*)d_in[4];
    const float* edge_w      = (const float*)d_in[5];
    const float* ln_g        = (const float*)d_in[6];
    const float* ln_b        = (const float*)d_in[7];
    const int*   t2ca        = (const int*)d_in[8];
    const int*   res_idx     = (const int*)d_in[9];
    // d_in[10] (asym_id) unused: chain_labels = zeros in the reference
    const int*   is_lig      = (const int*)d_in[11];

    float* out    = (float*)d_out;
    float* Eout   = out;                               // NEDGE * 128
    float* eidx_f = out + (size_t)NEDGE * EDGE_C_;     // NEDGE (ints as floats)
    float* dneb   = eidx_f + NEDGE;                    // NEDGE

    float* X  = (float*)d_ws;                          // NROWS*3 floats
    float* C1 = X + (size_t)NROWS * 3;                 // 65*128 floats

    hipLaunchKernelGGL(x_kernel, dim3(NROWS / 256), dim3(256), 0, stream,
                       coords, mask, t2ca, X);
    hipLaunchKernelGGL(c1_kernel, dim3((C1_ROWS * EDGE_C_ + 255) / 256), dim3(256), 0, stream,
                       pe_w, pe_b, edge_w, C1);
    hipLaunchKernelGGL(knn_kernel, dim3(NROWS / 2), dim3(128), 0, stream,
                       X, mask, eidx_f, dneb);
    hipLaunchKernelGGL(edge_kernel, dim3(NROWS / 4), dim3(256), 0, stream,
                       eidx_f, dneb, token_bonds, C1, edge_w,
                       ln_g, ln_b, res_idx, is_lig, Eout);
}

// Round 3
// 382.080 us; speedup vs baseline: 1.4534x; 1.1609x over previous
//
#include <hip/hip_runtime.h>
#include <math.h>

namespace {
constexpr int B_ = 4;
constexpr int N_ = 2048;
constexpr int K_ = 48;
constexpr int MAX_REL_ = 32;
constexpr int EDGE_C_ = 128;
constexpr int NUM_PE_ = 16;
constexpr int NROWS = B_ * N_;      // 8192
constexpr int NEDGE = NROWS * K_;   // 393216
constexpr int C1_ROWS = 2 * MAX_REL_ + 1;   // 65 reachable doff values
}

// ---------------- kernel 1: X = coords[center] * mask ----------------
__global__ __launch_bounds__(256) void x_kernel(const float* __restrict__ coords,
                                                const float* __restrict__ mask,
                                                const int* __restrict__ t2ca,
                                                float* __restrict__ X) {
    int r = blockIdx.x * 256 + threadIdx.x;
    if (r >= NROWS) return;
    int b = r >> 11;                 // N_ = 2048
    int c = t2ca[r];
    float m = mask[r];
    const float* s = coords + ((size_t)(b * N_ + c)) * 3;
    X[r * 3 + 0] = __fmul_rn(s[0], m);
    X[r * 3 + 1] = __fmul_rn(s[1], m);
    X[r * 3 + 2] = __fmul_rn(s[2], m);
}

// ---------------- kernel 1b: C1[d][c] = (pe_w[d,:]+pe_b) @ edge_w[0:16,c] ----
__global__ __launch_bounds__(256) void c1_kernel(const float* __restrict__ pe_w,
                                                 const float* __restrict__ pe_b,
                                                 const float* __restrict__ edge_w,
                                                 float* __restrict__ C1) {
    int idx = blockIdx.x * 256 + threadIdx.x;
    if (idx >= C1_ROWS * EDGE_C_) return;
    int d = idx >> 7, c = idx & 127;
    float acc = 0.0f;
    #pragma unroll
    for (int p = 0; p < NUM_PE_; ++p)
        acc = fmaf(pe_w[d * NUM_PE_ + p] + pe_b[p], edge_w[p * EDGE_C_ + c], acc);
    C1[idx] = acc;
}

// ---------------- kernel 2: masked distances + stable top-K (smallest) --------
// One wave per row; 4 rows per 256-thread block.
// Selection by radix-select over normalized 43-bit keys:
//   key = ((fbits(d_adj) - fbits_min) << 11) | j
// (monotone == (value asc, idx asc); keys distinct via idx bits).
// Per 8-bit pass: per-wave LDS histogram -> wave scan -> crossing bucket ->
// narrow candidate mask.  Exact 48th key T found in <=6 passes (usually 2-3).
// Then: flag keys<=T (exactly 48), compact to LDS, one wave bitonic sort of 64.
// No per-lane sort, no 16KB LDS spill, no 288-deep serial shuffle chain.
__global__ __launch_bounds__(256) void knn_kernel(const float* __restrict__ X,
                                                  const float* __restrict__ mask,
                                                  float* __restrict__ eidx_f,
                                                  float* __restrict__ dneb) {
    __shared__ unsigned s_hist[4][256];              // 4 KB (per-wave slices)
    __shared__ unsigned long long s_cbuf[4][64];     // 2 KB
    const int wv = threadIdx.x >> 6;
    const int lane = threadIdx.x & 63;
    const int row = blockIdx.x * 4 + wv;     // grid = NROWS/4
    const int b = row >> 11;

    const float xi0 = X[row * 3 + 0];
    const float xi1 = X[row * 3 + 1];
    const float xi2 = X[row * 3 + 2];
    const float mi = mask[row];
    const float* Xb = X + (size_t)b * N_ * 3;
    const float* mb = mask + b * N_;

    // pass 1: D = m2 * sqrt(fma-chain + 1e-6) into registers, row max
    float d[32];
    float lmax = -INFINITY;
    #pragma unroll
    for (int t = 0; t < 32; ++t) {
        int j = t * 64 + lane;
        float dx = __fsub_rn(xi0, Xb[j * 3 + 0]);
        float dy = __fsub_rn(xi1, Xb[j * 3 + 1]);
        float dz = __fsub_rn(xi2, Xb[j * 3 + 2]);
        float d2 = __fmaf_rn(dz, dz, __fmaf_rn(dx, dx, __fmul_rn(dy, dy)));
        float m2 = __fmul_rn(mi, mb[j]);
        float dd = __fmul_rn(m2, __fsqrt_rn(__fadd_rn(d2, 1e-6f)));
        d[t] = dd;
        lmax = fmaxf(lmax, dd);
    }
    #pragma unroll
    for (int off = 32; off; off >>= 1) lmax = fmaxf(lmax, __shfl_xor(lmax, off, 64));

    // pass 2: D_adjust = D + (1-m2)*Dmax (>=0 -> unsigned float-bit order ok);
    // wave min/max of the bit patterns for key normalization
    unsigned fb[32];
    unsigned fmin_l = 0xFFFFFFFFu, fmax_l = 0u;
    #pragma unroll
    for (int t = 0; t < 32; ++t) {
        int j = t * 64 + lane;
        float m2 = __fmul_rn(mi, mb[j]);
        float adj = __fadd_rn(d[t], __fmul_rn(__fsub_rn(1.0f, m2), lmax));
        unsigned u = __float_as_uint(adj);
        fb[t] = u;
        fmin_l = min(fmin_l, u);
        fmax_l = max(fmax_l, u);
    }
    #pragma unroll
    for (int off = 32; off; off >>= 1) {
        fmin_l = min(fmin_l, (unsigned)__shfl_xor((int)fmin_l, off, 64));
        fmax_l = max(fmax_l, (unsigned)__shfl_xor((int)fmax_l, off, 64));
    }
    const unsigned fminb = fmin_l;
    const unsigned range = fmax_l - fminb;
    const int vbits = (range == 0u) ? 0 : (32 - __clz((int)range));
    const int L = vbits + 11;   // meaningful bits in normalized key

    unsigned long long key[32];
    #pragma unroll
    for (int t = 0; t < 32; ++t)
        key[t] = ((unsigned long long)(fb[t] - fminb) << 11)
               | (unsigned long long)(unsigned)(t * 64 + lane);

    // ---- radix-select the exact 48th-smallest key T ----
    unsigned cand = 0xFFFFFFFFu;   // all 32 of my keys are boundary candidates
    int k_rem = K_;
    int sh = (L > 8) ? (L - 8) : 0;
    unsigned long long T = 0ull;

    while (true) {
        s_hist[wv][4 * lane + 0] = 0u;
        s_hist[wv][4 * lane + 1] = 0u;
        s_hist[wv][4 * lane + 2] = 0u;
        s_hist[wv][4 * lane + 3] = 0u;
        __asm__ volatile("s_waitcnt lgkmcnt(0)" ::: "memory");
        #pragma unroll
        for (int t = 0; t < 32; ++t) {
            if ((cand >> t) & 1u) {
                unsigned dig = (unsigned)(key[t] >> sh) & 255u;
                atomicAdd(&s_hist[wv][dig], 1u);
            }
        }
        __asm__ volatile("s_waitcnt lgkmcnt(0)" ::: "memory");
        const unsigned c0 = s_hist[wv][4 * lane + 0];
        const unsigned c1 = s_hist[wv][4 * lane + 1];
        const unsigned c2 = s_hist[wv][4 * lane + 2];
        const unsigned c3 = s_hist[wv][4 * lane + 3];
        const unsigned s4 = c0 + c1 + c2 + c3;
        unsigned inc = s4;
        #pragma unroll
        for (int off = 1; off < 64; off <<= 1) {
            unsigned o = (unsigned)__shfl_up((int)inc, off, 64);
            if (lane >= off) inc += o;
        }
        const unsigned ex = inc - s4;        // candidates in digits < 4*lane
        const unsigned e1 = ex + c0, e2 = e1 + c1, e3 = e2 + c2;
        const unsigned kr = (unsigned)k_rem;
        int digl = -1; unsigned below = 0u, bc = 0u;
        if (ex < kr && kr <= e1)           { digl = 4 * lane + 0; below = ex; bc = c0; }
        else if (e1 < kr && kr <= e2)      { digl = 4 * lane + 1; below = e1; bc = c1; }
        else if (e2 < kr && kr <= e3)      { digl = 4 * lane + 2; below = e2; bc = c2; }
        else if (e3 < kr && kr <= e3 + c3) { digl = 4 * lane + 3; below = e3; bc = c3; }

        unsigned long long bal = __ballot(digl >= 0);
        int src = __ffsll((long long)bal) - 1;
        const int dstar = __shfl(digl, src, 64);
        below = (unsigned)__shfl((int)below, src, 64);
        bc    = (unsigned)__shfl((int)bc, src, 64);
        k_rem -= (int)below;

        unsigned nc = 0u;
        unsigned long long myT = 0ull;
        #pragma unroll
        for (int t = 0; t < 32; ++t) {
            if (((cand >> t) & 1u) &&
                (((unsigned)(key[t] >> sh) & 255u) == (unsigned)dstar)) {
                nc |= (1u << t);
                myT = key[t];
            }
        }
        cand = nc;
        if (bc == 1u || sh == 0) {
            // unique boundary key (sh==0 forces bc==1: keys are distinct)
            unsigned long long b2 = __ballot(cand != 0u);
            int owner = __ffsll((long long)b2) - 1;
            T = __shfl(myT, owner, 64);
            break;
        }
        sh = (sh > 8) ? (sh - 8) : 0;
    }

    // ---- select keys <= T (exactly 48), compact to LDS ----
    unsigned selm = 0u; int scnt = 0;
    #pragma unroll
    for (int t = 0; t < 32; ++t) {
        if (key[t] <= T) { selm |= (1u << t); ++scnt; }
    }
    int isc = scnt;
    #pragma unroll
    for (int off = 1; off < 64; off <<= 1) {
        int o = __shfl_up(isc, off, 64);
        if (lane >= off) isc += o;
    }
    int pos = isc - scnt;
    #pragma unroll
    for (int t = 0; t < 32; ++t) {
        if ((selm >> t) & 1u) { s_cbuf[wv][pos] = key[t]; ++pos; }
    }
    __asm__ volatile("s_waitcnt lgkmcnt(0)" ::: "memory");
    unsigned long long kk = (lane < K_) ? s_cbuf[wv][lane] : ~0ull;

    // ---- wave bitonic sort of 64 (ascending) ----
    #pragma unroll
    for (int k2 = 2; k2 <= 64; k2 <<= 1) {
        #pragma unroll
        for (int j = k2 >> 1; j > 0; j >>= 1) {
            unsigned long long o = __shfl_xor(kk, j, 64);
            const bool dirAsc = ((lane & k2) == 0);
            const bool lower = ((lane & j) == 0);
            unsigned long long mn = (kk < o) ? kk : o;
            unsigned long long mx = (kk < o) ? o : kk;
            kk = (lower == dirAsc) ? mn : mx;
        }
    }

    if (lane < K_) {
        unsigned fbits = (unsigned)(kk >> 11) + fminb;   // de-normalize
        unsigned ji = (unsigned)(kk & 2047u);
        dneb[(size_t)row * K_ + lane] = __uint_as_float(fbits);
        eidx_f[(size_t)row * K_ + lane] = (float)ji;     // exact int-in-float
    }
}

// ---------------- kernel 3: features -> matmul -> LayerNorm ----------
// One WAVE per row (48 edges). Phase A: batched metadata gathers.
// Phase B: cooperative RBF exps into LDS. Phase C: per-edge matmul from
// precomputed C1 table + register weight columns, then wave LayerNorm.
__global__ __launch_bounds__(256, 4) void edge_kernel(const float* __restrict__ eidx_f,
                                                      const float* __restrict__ dneb,
                                                      const float* __restrict__ token_bonds,
                                                      const float* __restrict__ C1,
                                                      const float* __restrict__ edge_w,
                                                      const float* __restrict__ ln_g,
                                                      const float* __restrict__ ln_b,
                                                      const int* __restrict__ res_idx,
                                                      const int* __restrict__ is_lig,
                                                      float* __restrict__ Eout) {
    __shared__ float s_rbf[4][K_][NUM_PE_];   // 12 KB
    __shared__ float s_D[4][K_];              // 768 B
    const int tid = threadIdx.x;
    const int wv = tid >> 6;
    const int lane = tid & 63;
    const int row = blockIdx.x * 4 + wv;      // grid = NROWS/4, one row per wave
    const int b = row >> 11;

    // rbf (16) + bond (1) weight columns for this lane's two channels
    float w0[17], w1[17];
    #pragma unroll
    for (int p = 0; p < 17; ++p) {
        float2 w = ((const float2*)edge_w)[(NUM_PE_ + p) * 64 + lane];
        w0[p] = w.x; w1[p] = w.y;
    }
    const float g0 = ln_g[2 * lane], g1 = ln_g[2 * lane + 1];
    const float bb0 = ln_b[2 * lane], bb1 = ln_b[2 * lane + 1];

    const int ri = res_idx[row];
    const int li = is_lig[row];

    // ---- phase A: batched per-edge metadata (lanes 0..47, all in flight) ----
    int doff_l = 0; float tb_l = 0.0f;
    if (lane < K_) {
        const int e = row * K_ + lane;
        const int j = (int)(eidx_f[e] + 0.5f);
        const float D = dneb[e];
        const int jrow = b * N_ + j;
        const int rj = res_idx[jrow];
        const int lj = is_lig[jrow];
        float tb = token_bonds[(size_t)row * N_ + j];
        tb_l = (li | lj) ? tb : 0.0f;
        doff_l = min(max(ri - rj + MAX_REL_, 0), 2 * MAX_REL_);
        s_D[wv][lane] = D;
    }
    __syncthreads();

    // ---- phase B: all 48x16 RBF values cooperatively (12 exps per lane) ----
    #pragma unroll
    for (int t = 0; t < (K_ * NUM_PE_) / 64; ++t) {
        const int idx = t * 64 + lane;
        const int k = idx >> 4, r = idx & 15;
        const float D = s_D[wv][k];
        const float mu = 2.0f + (float)r * (4.0f / 3.0f);
        const float x = (D - mu) * 0.8f;     // /1.25
        s_rbf[wv][k][r] = __expf(-x * x);
    }
    __syncthreads();

    // ---- phase C: 48 edges, no global-latency chains in the loop ----
    float2* outp = (float2*)Eout + (size_t)row * K_ * 64 + lane;
    #pragma unroll 2
    for (int k = 0; k < K_; ++k) {
        const int doffk = __shfl(doff_l, k, 64);
        const float tbk = __shfl(tb_l, k, 64);
        const float2 c1 = *(const float2*)(C1 + ((size_t)doffk << 7) + 2 * lane);

        float rr[16];
        *(float4*)&rr[0]  = *(const float4*)&s_rbf[wv][k][0];
        *(float4*)&rr[4]  = *(const float4*)&s_rbf[wv][k][4];
        *(float4*)&rr[8]  = *(const float4*)&s_rbf[wv][k][8];
        *(float4*)&rr[12] = *(const float4*)&s_rbf[wv][k][12];

        float ax = 0.0f, ay = 0.0f;
        #pragma unroll
        for (int p = 0; p < 16; ++p) {
            ax = fmaf(rr[p], w0[p], ax);
            ay = fmaf(rr[p], w1[p], ay);
        }
        if (tbk != 0.0f) {                 // wave-uniform branch, ~1% taken
            ax = fmaf(tbk, w0[16], ax);
            ay = fmaf(tbk, w1[16], ay);
        }
        ax += c1.x; ay += c1.y;

        // LayerNorm over 128 channels (2 per lane)
        float s = ax + ay, sq = fmaf(ax, ax, ay * ay);
        #pragma unroll
        for (int off = 32; off; off >>= 1) {
            s  += __shfl_xor(s, off, 64);
            sq += __shfl_xor(sq, off, 64);
        }
        const float mu = s * (1.0f / 128.0f);
        const float var = sq * (1.0f / 128.0f) - mu * mu;
        const float rstd = rsqrtf(var + 1e-5f);
        const float ox = (ax - mu) * rstd * g0 + bb0;
        const float oy = (ay - mu) * rstd * g1 + bb1;
        outp[(size_t)k * 64] = make_float2(ox, oy);
    }
}

extern "C" void kernel_launch(void* const* d_in, const int* in_sizes, int n_in,
                              void* d_out, int out_size, void* d_ws, size_t ws_size,
                              hipStream_t stream) {
    const float* coords      = (const float*)d_in[0];
    const float* mask        = (const float*)d_in[1];
    const float* token_bonds = (const float*)d_in[2];
    const float* pe_w        = (const float*)d_in[3];
    const float* pe_b        = (const float*)d_in[4];
    const float* edge_w      = (const float*)d_in[5];
    const float* ln_g        = (const float*)d_in[6];
    const float* ln_b        = (const float*)d_in[7];
    const int*   t2ca        = (const int*)d_in[8];
    const int*   res_idx     = (const int*)d_in[9];
    // d_in[10] (asym_id) unused: chain_labels = zeros in the reference
    const int*   is_lig      = (const int*)d_in[11];

    float* out    = (float*)d_out;
    float* Eout   = out;                               // NEDGE * 128
    float* eidx_f = out + (size_t)NEDGE * EDGE_C_;     // NEDGE (ints as floats)
    float* dneb   = eidx_f + NEDGE;                    // NEDGE

    float* X  = (float*)d_ws;                          // NROWS*3 floats
    float* C1 = X + (size_t)NROWS * 3;                 // 65*128 floats

    hipLaunchKernelGGL(x_kernel, dim3(NROWS / 256), dim3(256), 0, stream,
                       coords, mask, t2ca, X);
    hipLaunchKernelGGL(c1_kernel, dim3((C1_ROWS * EDGE_C_ + 255) / 256), dim3(256), 0, stream,
                       pe_w, pe_b, edge_w, C1);
    hipLaunchKernelGGL(knn_kernel, dim3(NROWS / 4), dim3(256), 0, stream,
                       X, mask, eidx_f, dneb);
    hipLaunchKernelGGL(edge_kernel, dim3(NROWS / 4), dim3(256), 0, stream,
                       eidx_f, dneb, token_bonds, C1, edge_w,
                       ln_g, ln_b, res_idx, is_lig, Eout);
}